// Round 2
// baseline (1426.467 us; speedup 1.0000x reference)
//
#include <hip/hip_runtime.h>
#include <hip/hip_bf16.h>

typedef __attribute__((ext_vector_type(8))) short s16x8;
typedef __attribute__((ext_vector_type(4))) float f32x4;

#define MFMA16(a, b, c) __builtin_amdgcn_mfma_f32_16x16x32_bf16((a), (b), (c), 0, 0, 0)

__device__ __forceinline__ short f2bf(float f) {
    union { float f; unsigned u; } v; v.f = f;
    unsigned r = v.u + 0x7FFFu + ((v.u >> 16) & 1u);
    return (short)(r >> 16);
}

// ---------------------------------------------------------------------------
// Kernel 1: weight prep.
// WqkvT[m][n][kk] = W_m[kk][n] as bf16, kk padded 41->64 with zeros. m=0:q,1:k,2:v
// WoT[n][kk]      = Wo[kk][n]  as bf16.
// Grid is sized exactly: 4864*256 = 3*1024*64 + 1024*1024.
// ---------------------------------------------------------------------------
__global__ void prep_weights(const float* __restrict__ Wq, const float* __restrict__ Wk,
                             const float* __restrict__ Wv, const float* __restrict__ Wo,
                             short* __restrict__ WqkvT, short* __restrict__ WoT) {
    int i = blockIdx.x * 256 + threadIdx.x;
    const int T1 = 3 * 1024 * 64;
    if (i < T1) {
        int kk = i & 63, n = (i >> 6) & 1023, m = i >> 16;
        const float* W = (m == 0) ? Wq : ((m == 1) ? Wk : Wv);
        float v = (kk < 41) ? W[kk * 1024 + n] : 0.f;
        WqkvT[i] = f2bf(v);
    } else {
        int j = i - T1;                 // j < 1024*1024 by grid construction
        int kk = j & 1023, n = j >> 10;
        WoT[j] = f2bf(Wo[kk * 1024 + n]);
    }
}

// ---------------------------------------------------------------------------
// Kernel 2: fused QKV projection + attention, one block per (batch, head).
// Writes attention output (pre out-proj) as fp32 into d_out.
// S=41 padded to 48 rows (bias-garbage rows discarded), K dims padded to 64.
// ---------------------------------------------------------------------------
#define SP 48
#define PADW 72   // LDS bf16 row pad: 144B stride -> 2-way-max bank aliasing (free)

__global__ __launch_bounds__(256) void attn_kernel(
    const float* __restrict__ x, const float* __restrict__ bq,
    const float* __restrict__ bk, const float* __restrict__ bv,
    const float* __restrict__ rel, const short* __restrict__ WqkvT,
    float* __restrict__ out)
{
    __shared__ short xs[SP][PADW];    // x[b] bf16, rows 41..47 & cols 41..63 zero
    __shared__ short qs[SP][PADW];    // q/8 + bq/8
    __shared__ short ks_[SP][PADW];   // k
    __shared__ short vsT[64][PADW];   // v transposed: [d][t], t 48..63 zero
    __shared__ short ps[SP][PADW];    // softmax probs bf16, cols 41..63 zero
    __shared__ float ss[SP][49];      // scores fp32 (49-col pad: conflict-free col access)

    int b = blockIdx.x >> 4, h = blockIdx.x & 15;
    int tid = threadIdx.x;
    int lane = tid & 63, wave = tid >> 6;
    int l15 = lane & 15, l4 = lane >> 4;

    // -------- stage x[b] -> bf16 LDS (zero-padded); zero vsT tail cols --------
    const float* xb = x + (size_t)b * (41 * 41);
    for (int idx = tid; idx < SP * 64; idx += 256) {
        int r = idx >> 6, c = idx & 63;
        float v = (r < 41 && c < 41) ? xb[r * 41 + c] : 0.f;
        xs[r][c] = f2bf(v);
    }
    for (int idx = tid; idx < 64 * 16; idx += 256) {
        int d = idx >> 4, t = 48 + (idx & 15);
        vsT[d][t] = 0;
    }
    __syncthreads();

    // -------- Phase B: q,k,v = x @ W + bias (M=48, N=64, K=64). 36 tiles --------
    for (int t = wave; t < 36; t += 4) {
        int mat = t / 12, sub = t % 12, mt = sub >> 2, nt = sub & 3;
        f32x4 acc = {0.f, 0.f, 0.f, 0.f};
        const short* wbase = WqkvT + ((size_t)(mat * 1024 + h * 64 + nt * 16 + l15)) * 64 + l4 * 8;
        const short* abase = &xs[mt * 16 + l15][l4 * 8];
#pragma unroll
        for (int ksi = 0; ksi < 2; ++ksi) {
            s16x8 a = *(const s16x8*)(abase + ksi * 32);
            s16x8 bb = *(const s16x8*)(wbase + ksi * 32);
            acc = MFMA16(a, bb, acc);
        }
        const float* bias = (mat == 0) ? bq : ((mat == 1) ? bk : bv);
        float bval = bias[h * 64 + nt * 16 + l15];
        float scale = (mat == 0) ? 0.125f : 1.0f;   // fold 1/sqrt(dh) into q
#pragma unroll
        for (int i = 0; i < 4; ++i) {
            int row = mt * 16 + l4 * 4 + i;       // seq index
            int col = nt * 16 + l15;              // feature index
            short v = f2bf((acc[i] + bval) * scale);
            if (mat == 0) qs[row][col] = v;
            else if (mat == 1) ks_[row][col] = v;
            else vsT[col][row] = v;               // store V transposed for PV b-frags
        }
    }
    __syncthreads();

    // -------- Phase C: scores = q @ k^T (M=48, N=48, K=64). 9 tiles --------
    for (int t = wave; t < 9; t += 4) {
        int mt = t / 3, nt = t % 3;
        f32x4 acc = {0.f, 0.f, 0.f, 0.f};
#pragma unroll
        for (int ksi = 0; ksi < 2; ++ksi) {
            s16x8 a = *(const s16x8*)(&qs[mt * 16 + l15][ksi * 32 + l4 * 8]);
            s16x8 bb = *(const s16x8*)(&ks_[nt * 16 + l15][ksi * 32 + l4 * 8]);
            acc = MFMA16(a, bb, acc);
        }
#pragma unroll
        for (int i = 0; i < 4; ++i)
            ss[mt * 16 + l4 * 4 + i][nt * 16 + l15] = acc[i];
    }
    __syncthreads();

    // -------- Phase D: softmax rows (+ relative positional bias). cols>=41 masked --------
    if (tid < SP) {
        int r = tid;
        int rr = (r < 41) ? r : 40;               // clamp: rows >=41 are discarded garbage
        const float* relrow = rel + rr * 41;
        float m = -1e30f;
        for (int c = 0; c < 41; ++c) {
            float s = ss[r][c] + relrow[c];
            ss[r][c] = s;
            m = fmaxf(m, s);
        }
        float sum = 0.f;
        for (int c = 0; c < 41; ++c) {
            float e = __expf(ss[r][c] - m);
            ss[r][c] = e;
            sum += e;
        }
        float inv = 1.f / sum;
        for (int c = 0; c < 41; ++c) ps[r][c] = f2bf(ss[r][c] * inv);
        for (int c = 41; c < 64; ++c) ps[r][c] = 0;
    }
    __syncthreads();

    // -------- Phase E: out_h = P @ V (M=48, N=64, K=64). 12 tiles --------
    for (int t = wave; t < 12; t += 4) {
        int mt = t / 4, nt = t % 4;
        f32x4 acc = {0.f, 0.f, 0.f, 0.f};
#pragma unroll
        for (int ksi = 0; ksi < 2; ++ksi) {
            s16x8 a = *(const s16x8*)(&ps[mt * 16 + l15][ksi * 32 + l4 * 8]);
            s16x8 bb = *(const s16x8*)(&vsT[nt * 16 + l15][ksi * 32 + l4 * 8]);
            acc = MFMA16(a, bb, acc);
        }
#pragma unroll
        for (int i = 0; i < 4; ++i) {
            int s = mt * 16 + l4 * 4 + i;
            if (s < 41)
                out[((size_t)b * 41 + s) * 1024 + h * 64 + nt * 16 + l15] = acc[i];
        }
    }
}

// ---------------------------------------------------------------------------
// Kernel 3: out-projection GEMM, in place over d_out.
// C[m][n] = sum_k A[m][k] * Wo[k][n] + bo[n];  A = attn output (fp32 in d_out).
// BM=64, BN=1024 (full row -> A read exactly once), BK=32, 512 threads (8 waves),
// each wave owns 64x128 (4 row-tiles x 8 col-tiles of 16x16x32 MFMA).
// In-place safe: block reads only rows [m0,m0+64) and writes them only in epilogue.
// ---------------------------------------------------------------------------
__global__ __launch_bounds__(512) void proj_kernel(
    float* __restrict__ io, const short* __restrict__ WoT,
    const float* __restrict__ bo)
{
    __shared__ short As[2][64][40];   // 32 + 8 pad (80B stride -> 2-way aliasing, free)

    int m0 = blockIdx.x * 64;
    int tid = threadIdx.x;
    int lane = tid & 63, wave = tid >> 6;
    int l15 = lane & 15, l4 = lane >> 4;

    int srow = tid >> 3;          // 0..63
    int scol = (tid & 7) * 4;     // 0,4,...,28

    f32x4 acc[4][8];
#pragma unroll
    for (int mt = 0; mt < 4; ++mt)
#pragma unroll
        for (int nt = 0; nt < 8; ++nt) acc[mt][nt] = (f32x4){0.f, 0.f, 0.f, 0.f};

    const float* arow = io + (size_t)(m0 + srow) * 1024 + scol;

    // prologue: stage k-tile 0
    {
        f32x4 v = *(const f32x4*)(arow);
        union { short s[4]; unsigned long long u; } pk;
#pragma unroll
        for (int i = 0; i < 4; ++i) pk.s[i] = f2bf(v[i]);
        *(unsigned long long*)&As[0][srow][scol] = pk.u;
    }
    __syncthreads();

    for (int kk = 0; kk < 32; ++kk) {
        int cur = kk & 1;
        // issue next A tile load early (latency hidden under MFMAs)
        f32x4 nxt;
        bool have = (kk + 1 < 32);
        if (have) nxt = *(const f32x4*)(arow + (kk + 1) * 32);

        // fragments
        s16x8 afr[4];
#pragma unroll
        for (int mt = 0; mt < 4; ++mt)
            afr[mt] = *(const s16x8*)(&As[cur][mt * 16 + l15][l4 * 8]);
        s16x8 bfr[8];
#pragma unroll
        for (int nt = 0; nt < 8; ++nt) {
            const short* wb = WoT + (size_t)(wave * 128 + nt * 16 + l15) * 1024 + kk * 32 + l4 * 8;
            bfr[nt] = *(const s16x8*)wb;
        }
#pragma unroll
        for (int nt = 0; nt < 8; ++nt)
#pragma unroll
            for (int mt = 0; mt < 4; ++mt)
                acc[mt][nt] = MFMA16(afr[mt], bfr[nt], acc[mt][nt]);

        __syncthreads();   // all reads of As[cur^1] (prev iter) done before overwrite
        if (have) {
            union { short s[4]; unsigned long long u; } pk;
#pragma unroll
            for (int i = 0; i < 4; ++i) pk.s[i] = f2bf(nxt[i]);
            *(unsigned long long*)&As[cur ^ 1][srow][scol] = pk.u;
        }
        __syncthreads();   // As[cur^1] ready for next iter
    }

    // epilogue: add bias, write C rows (full 64 rows valid: 83968 % 64 == 0)
#pragma unroll
    for (int nt = 0; nt < 8; ++nt) {
        int col = wave * 128 + nt * 16 + l15;
        float bb = bo[col];
#pragma unroll
        for (int mt = 0; mt < 4; ++mt) {
#pragma unroll
            for (int i = 0; i < 4; ++i) {
                int row = m0 + mt * 16 + l4 * 4 + i;
                io[(size_t)row * 1024 + col] = acc[mt][nt][i] + bb;
            }
        }
    }
}

// ---------------------------------------------------------------------------
extern "C" void kernel_launch(void* const* d_in, const int* in_sizes, int n_in,
                              void* d_out, int out_size, void* d_ws, size_t ws_size,
                              hipStream_t stream) {
    const float* x   = (const float*)d_in[0];
    const float* Wq  = (const float*)d_in[1];
    const float* bq  = (const float*)d_in[2];
    const float* Wk  = (const float*)d_in[3];
    const float* bk  = (const float*)d_in[4];
    const float* Wv  = (const float*)d_in[5];
    const float* bv  = (const float*)d_in[6];
    const float* Wo  = (const float*)d_in[7];
    const float* bo  = (const float*)d_in[8];
    const float* rel = (const float*)d_in[9];

    short* WqkvT = (short*)d_ws;                    // 3*1024*64*2 = 384 KB
    short* WoT   = WqkvT + 3 * 1024 * 64;           // 1024*1024*2 = 2 MB
    float* out   = (float*)d_out;

    hipLaunchKernelGGL(prep_weights, dim3(4864), dim3(256), 0, stream,
                       Wq, Wk, Wv, Wo, WqkvT, WoT);
    hipLaunchKernelGGL(attn_kernel, dim3(2048 * 16), dim3(256), 0, stream,
                       x, bq, bk, bv, rel, WqkvT, out);
    hipLaunchKernelGGL(proj_kernel, dim3(83968 / 64), dim3(512), 0, stream,
                       out, WoT, bo);
}

// Round 4
// 1305.698 us; speedup vs baseline: 1.0925x; 1.0925x over previous
//
#include <hip/hip_runtime.h>
#include <hip/hip_bf16.h>

typedef __attribute__((ext_vector_type(8))) short s16x8;
typedef __attribute__((ext_vector_type(4))) float f32x4;

#define MFMA16(a, b, c) __builtin_amdgcn_mfma_f32_16x16x32_bf16((a), (b), (c), 0, 0, 0)

__device__ __forceinline__ short f2bf(float f) {
    union { float f; unsigned u; } v; v.f = f;
    unsigned r = v.u + 0x7FFFu + ((v.u >> 16) & 1u);
    return (short)(r >> 16);
}

// ---------------------------------------------------------------------------
// Kernel 1: weight prep — LDS-tiled transpose+cast (coalesced both sides).
// blocks 0..47:   Wq/Wk/Wv (41x1024, zero-pad K->64) -> WqkvT[m][n][64]
// blocks 48..303: Wo (1024x1024)                     -> WoT[n][1024]
// ---------------------------------------------------------------------------
__global__ __launch_bounds__(256) void prep_weights(
    const float* __restrict__ Wq, const float* __restrict__ Wk,
    const float* __restrict__ Wv, const float* __restrict__ Wo,
    short* __restrict__ WqkvT, short* __restrict__ WoT)
{
    __shared__ short sh[64][73];   // odd-ish pad: column reads spread banks

    int blk = blockIdx.x;
    const float* W; short* out; int K, Kp, k0, n0;
    if (blk < 48) {
        int m = blk >> 4, ntile = blk & 15;
        W = (m == 0) ? Wq : ((m == 1) ? Wk : Wv);
        out = WqkvT + m * 1024 * 64;
        K = 41; Kp = 64; k0 = 0; n0 = ntile * 64;
    } else {
        int t = blk - 48;
        W = Wo; out = WoT; K = 1024; Kp = 1024;
        k0 = (t >> 4) * 64; n0 = (t & 15) * 64;
    }
    int tid = threadIdx.x;
    // read 64x64 (k,n) tile, coalesced over n
#pragma unroll
    for (int p = 0; p < 16; ++p) {
        int kk = p * 4 + (tid >> 6);
        int nn = tid & 63;
        int k = k0 + kk;
        float v = (k < K) ? W[(size_t)k * 1024 + n0 + nn] : 0.f;
        sh[kk][nn] = f2bf(v);
    }
    __syncthreads();
    // write transposed, 16B per thread per pass
#pragma unroll
    for (int p = 0; p < 2; ++p) {
        int nn = p * 32 + (tid >> 3);
        int kk8 = (tid & 7) * 8;
        union { short s[8]; s16x8 v; } pk;
#pragma unroll
        for (int j = 0; j < 8; ++j) pk.s[j] = sh[kk8 + j][nn];
        *(s16x8*)&out[(size_t)(n0 + nn) * Kp + k0 + kk8] = pk.v;
    }
}

// ---------------------------------------------------------------------------
// Kernel 2: fused QKV + attention, one block per (batch, head).
// TOBF=1: write bf16 to ws (Abf). TOBF=0: write fp32 to d_out.
// Wave-parallel softmax: 16 lanes per row, shfl_xor reduce, regs-only.
// ---------------------------------------------------------------------------
#define SP 48
#define PADW 72

template<bool TOBF>
__global__ __launch_bounds__(256) void attn_kernel(
    const float* __restrict__ x, const float* __restrict__ bq,
    const float* __restrict__ bk, const float* __restrict__ bv,
    const float* __restrict__ rel, const short* __restrict__ WqkvT,
    void* __restrict__ outp)
{
    __shared__ short xs[SP][PADW];    // overlaid by ps after softmax (xs dead post-B)
    __shared__ short qs[SP][PADW];
    __shared__ short ks_[SP][PADW];
    __shared__ short vsT[64][PADW];
    __shared__ float ss[SP][48];      // stride 48 f32: rows 2-way aliased (free)

    short (*ps)[PADW] = xs;           // overlay

    int b = blockIdx.x >> 4, h = blockIdx.x & 15;
    int tid = threadIdx.x;
    int lane = tid & 63, wave = tid >> 6;
    int l15 = lane & 15, l4 = lane >> 4;

    // -------- stage x[b] -> bf16 LDS (zero-padded); zero vsT tail cols --------
    const float* xb = x + (size_t)b * (41 * 41);
    for (int idx = tid; idx < SP * 64; idx += 256) {
        int r = idx >> 6, c = idx & 63;
        float v = (r < 41 && c < 41) ? xb[r * 41 + c] : 0.f;
        xs[r][c] = f2bf(v);
    }
    for (int idx = tid; idx < 64 * 16; idx += 256)
        vsT[idx >> 4][48 + (idx & 15)] = 0;
    __syncthreads();

    // -------- Phase B: q,k,v = x @ W + bias (M=48,N=64,K=64). 36 tiles --------
    for (int t = wave; t < 36; t += 4) {
        int mat = t / 12, sub = t % 12, mt = sub >> 2, nt = sub & 3;
        f32x4 acc = {0.f, 0.f, 0.f, 0.f};
        const short* wbase = WqkvT + ((size_t)(mat * 1024 + h * 64 + nt * 16 + l15)) * 64 + l4 * 8;
        const short* abase = &xs[mt * 16 + l15][l4 * 8];
#pragma unroll
        for (int ksi = 0; ksi < 2; ++ksi) {
            s16x8 a = *(const s16x8*)(abase + ksi * 32);
            s16x8 bb = *(const s16x8*)(wbase + ksi * 32);
            acc = MFMA16(a, bb, acc);
        }
        const float* bias = (mat == 0) ? bq : ((mat == 1) ? bk : bv);
        float bval = bias[h * 64 + nt * 16 + l15];
        float scale = (mat == 0) ? 0.125f : 1.0f;   // fold 1/sqrt(dh) into q
#pragma unroll
        for (int i = 0; i < 4; ++i) {
            int row = mt * 16 + l4 * 4 + i;
            int col = nt * 16 + l15;
            short v = f2bf((acc[i] + bval) * scale);
            if (mat == 0) qs[row][col] = v;
            else if (mat == 1) ks_[row][col] = v;
            else vsT[col][row] = v;
        }
    }
    __syncthreads();

    // -------- Phase C: scores = q @ k^T + rel (M=48,N=48,K=64). 9 tiles --------
    for (int t = wave; t < 9; t += 4) {
        int mt = t / 3, nt = t % 3;
        f32x4 acc = {0.f, 0.f, 0.f, 0.f};
#pragma unroll
        for (int ksi = 0; ksi < 2; ++ksi) {
            s16x8 a = *(const s16x8*)(&qs[mt * 16 + l15][ksi * 32 + l4 * 8]);
            s16x8 bb = *(const s16x8*)(&ks_[nt * 16 + l15][ksi * 32 + l4 * 8]);
            acc = MFMA16(a, bb, acc);
        }
#pragma unroll
        for (int i = 0; i < 4; ++i) {
            int row = mt * 16 + l4 * 4 + i;
            int col = nt * 16 + l15;
            int rr = (row < 41) ? row : 40;
            float rv = (col < 41) ? rel[rr * 41 + col] : 0.f;
            ss[row][col] = acc[i] + rv;
        }
    }
    __syncthreads();

    // -------- Phase D: wave-parallel softmax. 16 lanes/row, 4 rows/wave/pass --------
#pragma unroll
    for (int p = 0; p < 3; ++p) {
        int r = wave * 4 + p * 16 + l4;          // 0..47, all distinct
        float v0 = ss[r][l15];
        float v1 = ss[r][l15 + 16];
        bool has2 = (l15 < 9);                    // cols 32..40
        float v2 = has2 ? ss[r][l15 + 32] : -3.0e38f;
        float m = fmaxf(fmaxf(v0, v1), v2);
#pragma unroll
        for (int off = 8; off; off >>= 1) m = fmaxf(m, __shfl_xor(m, off, 16));
        float e0 = __expf(v0 - m), e1 = __expf(v1 - m);
        float e2 = has2 ? __expf(v2 - m) : 0.f;
        float s = e0 + e1 + e2;
#pragma unroll
        for (int off = 8; off; off >>= 1) s += __shfl_xor(s, off, 16);
        float inv = 1.f / s;
        ps[r][l15]      = f2bf(e0 * inv);
        ps[r][l15 + 16] = f2bf(e1 * inv);
        ps[r][l15 + 32] = has2 ? f2bf(e2 * inv) : (short)0;  // cols 41..47 -> 0
        ps[r][l15 + 48] = 0;                                  // cols 48..63 -> 0
    }
    __syncthreads();

    // -------- Phase E: out_h = P @ V (M=48,N=64,K=64). 12 tiles --------
    for (int t = wave; t < 12; t += 4) {
        int mt = t / 4, nt = t % 4;
        f32x4 acc = {0.f, 0.f, 0.f, 0.f};
#pragma unroll
        for (int ksi = 0; ksi < 2; ++ksi) {
            s16x8 a = *(const s16x8*)(&ps[mt * 16 + l15][ksi * 32 + l4 * 8]);
            s16x8 bb = *(const s16x8*)(&vsT[nt * 16 + l15][ksi * 32 + l4 * 8]);
            acc = MFMA16(a, bb, acc);
        }
#pragma unroll
        for (int i = 0; i < 4; ++i) {
            int s = mt * 16 + l4 * 4 + i;
            if (s < 41) {
                size_t off = ((size_t)b * 41 + s) * 1024 + h * 64 + nt * 16 + l15;
                if (TOBF) ((short*)outp)[off] = f2bf(acc[i]);
                else      ((float*)outp)[off] = acc[i];
            }
        }
    }
}

// ---------------------------------------------------------------------------
// Kernel 3a (big-ws path): out-proj from bf16 A in ws.
// BM=64, BN=256, BK=64, 256 threads (4 waves, each owns 64x64 = 4x4 acc).
// A tile [64 rows][8 slots of 16B], XOR-swizzled: phys slot u holds logical
// slot u^(row&7)  ->  ds_read_b128 conflict-free (T2). B-frags from L2 (WoT hot).
// ---------------------------------------------------------------------------
__global__ __launch_bounds__(256) void proj_a(
    const short* __restrict__ Ab, float* __restrict__ out,
    const short* __restrict__ WoT, const float* __restrict__ bo)
{
    __shared__ short As[2][64 * 64];  // per row: 64 bf16 = 128B = 8 slots

    int m0 = (blockIdx.x >> 2) * 64;
    int n0 = (blockIdx.x & 3) * 256;
    int tid = threadIdx.x, lane = tid & 63, wave = tid >> 6;
    int l15 = lane & 15, l4 = lane >> 4;

    f32x4 acc[4][4];
#pragma unroll
    for (int mt = 0; mt < 4; ++mt)
#pragma unroll
        for (int nt = 0; nt < 4; ++nt) acc[mt][nt] = (f32x4){0.f, 0.f, 0.f, 0.f};

    // staging map: lane covers 32B of one row (2 slots)
    int srow = tid >> 2;
    int part = tid & 3;
    const short* asrc = Ab + (size_t)(m0 + srow) * 1024 + part * 16;
    int u0 = (2 * part) ^ (srow & 7);
    int u1 = (2 * part + 1) ^ (srow & 7);
    int d0 = srow * 64 + u0 * 8;
    int d1 = srow * 64 + u1 * 8;

    // prologue: stage kt=0 into buf0
    {
        s16x8 r0 = *(const s16x8*)(asrc);
        s16x8 r1 = *(const s16x8*)(asrc + 8);
        *(s16x8*)&As[0][d0] = r0;
        *(s16x8*)&As[0][d1] = r1;
    }
    __syncthreads();

    const short* wbase = WoT + (size_t)(n0 + wave * 64) * 1024;

    for (int kt = 0; kt < 16; ++kt) {
        int cur = kt & 1;
        s16x8 nr0, nr1;
        bool have = (kt < 15);
        if (have) {                          // issue next-tile loads early (T14)
            const short* s = asrc + (kt + 1) * 64;
            nr0 = *(const s16x8*)(s);
            nr1 = *(const s16x8*)(s + 8);
        }
#pragma unroll
        for (int ksi = 0; ksi < 2; ++ksi) {
            s16x8 afr[4], bfr[4];
#pragma unroll
            for (int mt = 0; mt < 4; ++mt) {
                int row = mt * 16 + l15;
                int u = (ksi * 4 + l4) ^ (row & 7);
                afr[mt] = *(const s16x8*)&As[cur][row * 64 + u * 8];
            }
#pragma unroll
            for (int nt = 0; nt < 4; ++nt)
                bfr[nt] = *(const s16x8*)(wbase + (size_t)(nt * 16 + l15) * 1024
                                          + kt * 64 + ksi * 32 + l4 * 8);
#pragma unroll
            for (int nt = 0; nt < 4; ++nt)
#pragma unroll
                for (int mt = 0; mt < 4; ++mt)
                    acc[mt][nt] = MFMA16(afr[mt], bfr[nt], acc[mt][nt]);
        }
        __syncthreads();                     // reads of As[cur] done
        if (have) {
            *(s16x8*)&As[cur ^ 1][d0] = nr0;
            *(s16x8*)&As[cur ^ 1][d1] = nr1;
        }
        __syncthreads();                     // As[cur^1] ready
    }

    // epilogue: bias + fp32 store (writes d_out fully; attn never touched it)
#pragma unroll
    for (int nt = 0; nt < 4; ++nt) {
        int col = n0 + wave * 64 + nt * 16 + l15;
        float bb = bo[col];
#pragma unroll
        for (int mt = 0; mt < 4; ++mt)
#pragma unroll
            for (int i = 0; i < 4; ++i)
                out[(size_t)(m0 + mt * 16 + l4 * 4 + i) * 1024 + col] = acc[mt][nt][i] + bb;
    }
}

// ---------------------------------------------------------------------------
// Kernel 3b (fallback, verified round-2): in-place fp32 proj, BM=64, BN=1024.
// In-place safe ONLY at BN=1024 (block reads all K of its own rows, no sharing).
// ---------------------------------------------------------------------------
__global__ __launch_bounds__(512) void proj_b(
    float* __restrict__ io, const short* __restrict__ WoT,
    const float* __restrict__ bo)
{
    __shared__ short As[2][64][40];

    int m0 = blockIdx.x * 64;
    int tid = threadIdx.x;
    int lane = tid & 63, wave = tid >> 6;
    int l15 = lane & 15, l4 = lane >> 4;
    int srow = tid >> 3;
    int scol = (tid & 7) * 4;

    f32x4 acc[4][8];
#pragma unroll
    for (int mt = 0; mt < 4; ++mt)
#pragma unroll
        for (int nt = 0; nt < 8; ++nt) acc[mt][nt] = (f32x4){0.f, 0.f, 0.f, 0.f};

    const float* arow = io + (size_t)(m0 + srow) * 1024 + scol;
    {
        f32x4 v = *(const f32x4*)(arow);
        union { short s[4]; unsigned long long u; } pk;
#pragma unroll
        for (int i = 0; i < 4; ++i) pk.s[i] = f2bf(v[i]);
        *(unsigned long long*)&As[0][srow][scol] = pk.u;
    }
    __syncthreads();

    for (int kk = 0; kk < 32; ++kk) {
        int cur = kk & 1;
        f32x4 nxt;
        bool have = (kk + 1 < 32);
        if (have) nxt = *(const f32x4*)(arow + (kk + 1) * 32);

        s16x8 afr[4];
#pragma unroll
        for (int mt = 0; mt < 4; ++mt)
            afr[mt] = *(const s16x8*)(&As[cur][mt * 16 + l15][l4 * 8]);
        s16x8 bfr[8];
#pragma unroll
        for (int nt = 0; nt < 8; ++nt)
            bfr[nt] = *(const s16x8*)(WoT + (size_t)(wave * 128 + nt * 16 + l15) * 1024
                                      + kk * 32 + l4 * 8);
#pragma unroll
        for (int nt = 0; nt < 8; ++nt)
#pragma unroll
            for (int mt = 0; mt < 4; ++mt)
                acc[mt][nt] = MFMA16(afr[mt], bfr[nt], acc[mt][nt]);

        __syncthreads();
        if (have) {
            union { short s[4]; unsigned long long u; } pk;
#pragma unroll
            for (int i = 0; i < 4; ++i) pk.s[i] = f2bf(nxt[i]);
            *(unsigned long long*)&As[cur ^ 1][srow][scol] = pk.u;
        }
        __syncthreads();
    }

#pragma unroll
    for (int nt = 0; nt < 8; ++nt) {
        int col = wave * 128 + nt * 16 + l15;
        float bb = bo[col];
#pragma unroll
        for (int mt = 0; mt < 4; ++mt)
#pragma unroll
            for (int i = 0; i < 4; ++i)
                io[(size_t)(m0 + mt * 16 + l4 * 4 + i) * 1024 + col] = acc[mt][nt][i] + bb;
    }
}

// ---------------------------------------------------------------------------
extern "C" void kernel_launch(void* const* d_in, const int* in_sizes, int n_in,
                              void* d_out, int out_size, void* d_ws, size_t ws_size,
                              hipStream_t stream) {
    const float* x   = (const float*)d_in[0];
    const float* Wq  = (const float*)d_in[1];
    const float* bq  = (const float*)d_in[2];
    const float* Wk  = (const float*)d_in[3];
    const float* bk  = (const float*)d_in[4];
    const float* Wv  = (const float*)d_in[5];
    const float* bv  = (const float*)d_in[6];
    const float* Wo  = (const float*)d_in[7];
    const float* bo  = (const float*)d_in[8];
    const float* rel = (const float*)d_in[9];

    short* WqkvT = (short*)d_ws;                    // 384 KB
    short* WoT   = WqkvT + 3 * 1024 * 64;           // 2 MB
    short* Abf   = WoT + 1024 * 1024;               // 164 MB (big-ws path only)
    float* out   = (float*)d_out;

    const size_t ABF_BYTES = (size_t)83968 * 1024 * 2;
    const size_t W_BYTES   = (3 * 1024 * 64 + 1024 * 1024) * sizeof(short);
    bool bigws = ws_size >= W_BYTES + ABF_BYTES;

    hipLaunchKernelGGL(prep_weights, dim3(304), dim3(256), 0, stream,
                       Wq, Wk, Wv, Wo, WqkvT, WoT);
    if (bigws) {
        hipLaunchKernelGGL((attn_kernel<true>), dim3(2048 * 16), dim3(256), 0, stream,
                           x, bq, bk, bv, rel, WqkvT, (void*)Abf);
        hipLaunchKernelGGL(proj_a, dim3(1312 * 4), dim3(256), 0, stream,
                           Abf, out, WoT, bo);
    } else {
        hipLaunchKernelGGL((attn_kernel<false>), dim3(2048 * 16), dim3(256), 0, stream,
                           x, bq, bk, bv, rel, WqkvT, (void*)out);
        hipLaunchKernelGGL(proj_b, dim3(83968 / 64), dim3(512), 0, stream,
                           out, WoT, bo);
    }
}